// Round 6
// baseline (338.039 us; speedup 1.0000x reference)
//
#include <hip/hip_runtime.h>

// FSUConv2d stochastic-computing conv. N=8,C=32,H=W=16,OC=64,K=3,PAD=1,RLEN=256.
// CKK=288, B=2048. Essential stream: wrdx_i1/wrdx_i0 [2048,64,288] i32 = 302 MB.
//
// Math (verified R1/R2, absmax 0): per element
//   m  = x ? -1 : 0
//   I  = m ? i1  : ~i0
//   Wp = m ? w-1 : 255-w
//   bit = ( (int)(brev(I)>>24) <= Wp )   [signed; exact at w=0/256]
// out[b,o] = sum_k bit + (b_bin[o] > rev8(brdx[o]))
//
// R5: async global->LDS DMA (global_load_lds width=16, m97 pattern).
// Evidence trail: R1/R2 proved the compiler sinks register prefetches
// (VGPR 44/56) leaving ~2 outstanding loads/wave -> ~2.7 TB/s consumption
// cap; R4 proved register-level asm pipelining corrupts data (async writes
// vs extract copies). global_load_lds has NO destination register: 18
// fire-and-forget 1KB issues per wave, drained by __syncthreads' vmcnt(0).
// 47.4 KB LDS/block -> 3 blocks/CU, phases stagger across blocks.

#define CH   32
#define OCN  64
#define CKK  288
#define LL   256
#define BB   2048

__device__ __forceinline__ void async_cp16(const unsigned* g, unsigned* l) {
    __builtin_amdgcn_global_load_lds(
        (const __attribute__((address_space(1))) unsigned*)g,
        (__attribute__((address_space(3))) unsigned*)l, 16, 0, 0);
}

__device__ __forceinline__ int elem(int i1, int i0, int m, int ws) {
    int u   = ws - 1;            // x=1 threshold
    int v   = 255 - ws;          // x=0 threshold
    int ni0 = ~i0;
    int I   = ni0 ^ ((i1 ^ ni0) & m);   // v_bfi: m ? i1 : ~i0
    int Wp  = v   ^ ((u  ^ v)  & m);    // v_bfi: m ? w-1 : 255-w
    return ((int)(__brev((unsigned)I) >> 24) <= Wp) ? 1 : 0;
}

__global__ __launch_bounds__(128) void fsu_main(
    const float* __restrict__ x,      // [8,32,16,16]
    const float* __restrict__ w_bin,  // [64,288]
    const float* __restrict__ b_bin,  // [64]
    const int*   __restrict__ wrdx1,  // [2048,64,288]
    const int*   __restrict__ wrdx0,  // [2048,64,288]
    const int*   __restrict__ brdx,   // [64]
    float*       __restrict__ out)    // [8,64,16,16]
{
    // block = (b, oq): rows o in [oq*16, oq*16+16). 2 waves; wave w owns the
    // 8 contiguous rows o = oq*16 + w*8 + g (g = lane>>3); lane j = lane&7
    // consumes int4 chunks c = j+8t, t=0..8 (72 chunks = 288 ints per row).
    __shared__ __align__(16) unsigned s_i1[2][8 * CKK];  // 18432 B
    __shared__ __align__(16) unsigned s_i0[2][8 * CKK];  // 18432 B
    __shared__ __align__(16) short    s_w[16 * 292];     // 9344 B (padded)
    __shared__ __align__(16) int      s_x[CKK];          // 1152 B
    __shared__             float      s_b[16];

    const int tid  = threadIdx.x;
    const int wave = tid >> 6;
    const int lane = tid & 63;
    const int b    = blockIdx.x >> 2;
    const int oq   = blockIdx.x & 3;
    const int n = b >> 8, l = b & 255, h = l >> 4, w0 = l & 15;
    const int obase = oq * 16;

    // ---- 1) DMA issue FIRST (wave-uniform, all 64 lanes active) ----
    {
        const size_t span = ((size_t)b * OCN + obase + wave * 8) * CKK;
        const unsigned* g1 = (const unsigned*)wrdx1 + span + lane * 4;
        const unsigned* g0 = (const unsigned*)wrdx0 + span + lane * 4;
        unsigned* l1 = &s_i1[wave][0];
        unsigned* l0 = &s_i0[wave][0];
#pragma unroll
        for (int s = 0; s < 9; ++s) {
            async_cp16(g1 + s * 256, l1 + s * 256);  // 1 KB per issue
            async_cp16(g0 + s * 256, l0 + s * 256);
        }
    }

    // ---- 2) small staging (overlaps DMA flight; drained at barrier) ----
    for (int i = tid; i < 16 * CKK; i += 128) {
        int r = i / CKK, k = i - r * CKK;
        s_w[r * 292 + k] = (short)(int)w_bin[(obase + r) * CKK + k];
    }
    for (int k = tid; k < CKK; k += 128) {
        int c  = k / 9, rr = k - c * 9;
        int kh = rr / 3, kw = rr - kh * 3;
        int ih = h + kh - 1, iw = w0 + kw - 1;
        float v = 0.f;
        if ((unsigned)ih < 16u && (unsigned)iw < 16u)
            v = x[((n * CH + c) * 16 + ih) * 16 + iw];
        s_x[k] = (v != 0.f) ? -1 : 0;
    }
    if (tid < 16) {
        int o = obase + tid;
        s_b[tid] = (b_bin[o] > (float)(__brev((unsigned)brdx[o]) >> 24)) ? 1.f : 0.f;
    }
    __syncthreads();   // compiler emits s_waitcnt vmcnt(0) -> all DMA landed

    // ---- 3) consume (pure LDS + VALU, no vmem until the final store) ----
    const int g = lane >> 3;
    const int j = lane & 7;
    const unsigned* r1 = &s_i1[wave][g * CKK];
    const unsigned* r0 = &s_i0[wave][g * CKK];
    const short*    wr = &s_w[(wave * 8 + g) * 292];

    int cnt = 0;
#pragma unroll
    for (int t = 0; t < 9; ++t) {
        const int c = j + (t << 3);
        int4   q1 = *(const int4*)(r1 + (c << 2));
        int4   q0 = *(const int4*)(r0 + (c << 2));
        int4   xm = *(const int4*)(s_x + (c << 2));       // broadcast over g
        short4 wv = *(const short4*)(wr + (c << 2));
        cnt += elem(q1.x, q0.x, xm.x, (int)wv.x);
        cnt += elem(q1.y, q0.y, xm.y, (int)wv.y);
        cnt += elem(q1.z, q0.z, xm.z, (int)wv.z);
        cnt += elem(q1.w, q0.w, xm.w, (int)wv.w);
    }

    // reduce over the 8 j-lanes of each o-group
    cnt += __shfl_down(cnt, 4);
    cnt += __shfl_down(cnt, 2);
    cnt += __shfl_down(cnt, 1);

    if (j == 0) {
        int o = obase + wave * 8 + g;
        out[((size_t)n * OCN + o) * LL + l] = (float)cnt + s_b[wave * 8 + g];
    }
}

extern "C" void kernel_launch(void* const* d_in, const int* in_sizes, int n_in,
                              void* d_out, int out_size, void* d_ws, size_t ws_size,
                              hipStream_t stream) {
    const float* x     = (const float*)d_in[0];
    const float* w_bin = (const float*)d_in[1];
    const float* b_bin = (const float*)d_in[2];
    // d_in[3] = rng — closed-form bit-reversal
    const int*   wrdx1 = (const int*)d_in[4];
    const int*   wrdx0 = (const int*)d_in[5];
    const int*   brdx  = (const int*)d_in[6];
    float*       out   = (float*)d_out;

    dim3 grid(BB * 4), block(128);   // block = (b, quarter-of-o)
    fsu_main<<<grid, block, 0, stream>>>(x, w_bin, b_bin, wrdx1, wrdx0, brdx, out);
}